// Round 8
// baseline (218.132 us; speedup 1.0000x reference)
//
#include <hip/hip_runtime.h>
#include <math.h>

#define N_ 16
#define C_ 256
#define H_ 128
#define W_ 128
#define TC_ 8
#define S_ 257   // H + W + 1
#define EPS_ 1e-5f
#define NBLK 1024
#define PPB 4    // planes per block; b = n*64 + cg, channels c0 = cg*4 .. +4

// ws layout (floats):
//   xcat: [N*C][S][2] = 2105344
//   cnt : 16 per-n barrier counters, stride 16 uints (64 B)
#define XCAT_OFF 0
#define CNT_OFF  2105344

typedef float f4n __attribute__((ext_vector_type(4)));

__global__ __launch_bounds__(256, 4) void mega(
    const float* __restrict__ x,
    const float* __restrict__ w1, const float* __restrict__ b1,
    const float* __restrict__ gam, const float* __restrict__ bet,
    const float* __restrict__ mu, const float* __restrict__ var,
    const float* __restrict__ w2, const float* __restrict__ b2,
    const float* __restrict__ w3, const float* __restrict__ b3,
    const float* __restrict__ w4, const float* __restrict__ b4,
    float* __restrict__ xcat, unsigned* __restrict__ cnt,
    float* __restrict__ out)
{
    const int b = blockIdx.x;
    const int n = b >> 6, cg = b & 63, c0 = cg * 4;
    const int tid = threadIdx.x;
    __shared__ __align__(16) float smf[7744];   // 31 KB, phase-overlaid

    // ---------------- phase 1: stats for my 4 planes -> xcat ----------------
    // Shuffle-based row reduce (no big LDS); scr double-buffered by plane
    // parity -> ONE __syncthreads per plane.
    {
        float4* scrS = reinterpret_cast<float4*>(smf);         // [2][128]
        float4* scrM = reinterpret_cast<float4*>(smf) + 256;   // [2][128]
        const int rg = tid >> 5, l = tid & 31;

        for (int u = 0; u < PPB; ++u) {
            const int p = b * PPB + u;
            const float4* xt = reinterpret_cast<const float4*>(x) + (size_t)p * 4096;
            float2* xcat2 = reinterpret_cast<float2*>(xcat) + (size_t)p * S_;

            float4 cs = make_float4(0.f, 0.f, 0.f, 0.f);
            float4 cm = make_float4(-INFINITY, -INFINITY, -INFINITY, -INFINITY);

            #pragma unroll
            for (int k = 0; k < 16; ++k) {
                const float4 v = xt[k * 256 + tid];
                cs.x += v.x; cs.y += v.y; cs.z += v.z; cs.w += v.w;
                cm.x = fmaxf(cm.x, v.x); cm.y = fmaxf(cm.y, v.y);
                cm.z = fmaxf(cm.z, v.z); cm.w = fmaxf(cm.w, v.w);

                float rs = (v.x + v.y) + (v.z + v.w);
                float rm = fmaxf(fmaxf(v.x, v.y), fmaxf(v.z, v.w));
                #pragma unroll
                for (int m = 16; m >= 1; m >>= 1) {
                    rs += __shfl_xor(rs, m);
                    rm = fmaxf(rm, __shfl_xor(rm, m));
                }
                if (l == 0)
                    xcat2[k * 8 + rg] = make_float2(rs * (1.f / 128.f), rm);
            }

            cs.x += __shfl_xor(cs.x, 32); cs.y += __shfl_xor(cs.y, 32);
            cs.z += __shfl_xor(cs.z, 32); cs.w += __shfl_xor(cs.w, 32);
            cm.x = fmaxf(cm.x, __shfl_xor(cm.x, 32));
            cm.y = fmaxf(cm.y, __shfl_xor(cm.y, 32));
            cm.z = fmaxf(cm.z, __shfl_xor(cm.z, 32));
            cm.w = fmaxf(cm.w, __shfl_xor(cm.w, 32));

            float4* sS = scrS + (u & 1) * 128;
            float4* sM = scrM + (u & 1) * 128;
            const int wv = tid >> 6, ln = tid & 63;
            if (ln < 32) { sS[wv * 32 + ln] = cs; sM[wv * 32 + ln] = cm; }
            __syncthreads();

            if (tid < 32) {   // wave 0: combine 4 waves; cols + global
                const float4 s0 = sS[tid],      s1 = sS[32 + tid],
                             s2 = sS[64 + tid], s3 = sS[96 + tid];
                const float4 m0 = sM[tid],      m1 = sM[32 + tid],
                             m2 = sM[64 + tid], m3 = sM[96 + tid];
                float4 S, M;
                S.x = (s0.x + s1.x) + (s2.x + s3.x);
                S.y = (s0.y + s1.y) + (s2.y + s3.y);
                S.z = (s0.z + s1.z) + (s2.z + s3.z);
                S.w = (s0.w + s1.w) + (s2.w + s3.w);
                M.x = fmaxf(fmaxf(m0.x, m1.x), fmaxf(m2.x, m3.x));
                M.y = fmaxf(fmaxf(m0.y, m1.y), fmaxf(m2.y, m3.y));
                M.z = fmaxf(fmaxf(m0.z, m1.z), fmaxf(m2.z, m3.z));
                M.w = fmaxf(fmaxf(m0.w, m1.w), fmaxf(m2.w, m3.w));

                const int w0 = 4 * tid;
                xcat2[128 + w0 + 0] = make_float2(S.x * (1.f / 128.f), M.x);
                xcat2[128 + w0 + 1] = make_float2(S.y * (1.f / 128.f), M.y);
                xcat2[128 + w0 + 2] = make_float2(S.z * (1.f / 128.f), M.z);
                xcat2[128 + w0 + 3] = make_float2(S.w * (1.f / 128.f), M.w);

                float gs = (S.x + S.y) + (S.z + S.w);
                float gm = fmaxf(fmaxf(M.x, M.y), fmaxf(M.z, M.w));
                #pragma unroll
                for (int m = 16; m >= 1; m >>= 1) {
                    gs += __shfl_xor(gs, m);
                    gm = fmaxf(gm, __shfl_xor(gm, m));
                }
                if (tid == 0) xcat2[256] = make_float2(gs * (1.f / 16384.f), gm);
            }
        }
    }

    // ------------- per-n barrier: wait for my 63 siblings -------------------
    // Arrival: one RELEASE add. Spin: RELAXED loads (acquire-per-poll cost
    // ~1.4 ms in round 6). One ACQUIRE after spin exit.
    __syncthreads();
    if (tid == 0) {
        unsigned* c = cnt + n * 16;
        __hip_atomic_fetch_add(c, 1u, __ATOMIC_RELEASE, __HIP_MEMORY_SCOPE_AGENT);
        while (__hip_atomic_load(c, __ATOMIC_RELAXED, __HIP_MEMORY_SCOPE_AGENT) < 64u)
            __builtin_amdgcn_s_sleep(16);
        (void)__hip_atomic_load(c, __ATOMIC_ACQUIRE, __HIP_MEMORY_SCOPE_AGENT);
    }
    __syncthreads();

    // ---------------- phase 2: y[n] (redundant per block), own a_h/a_w/a_c --
    // LDS layout (floats): w1s 0..2048 | ys 2048..6417 (257*17) |
    //   red2 6420..6692 (16*17) | acs 6692..6696 | awl 6704..7216 (16B-al) |
    //   ahl 7216..7728
    float* w1s  = smf;
    float* ys   = smf + 2048;
    float* red2 = smf + 6420;
    float* acs  = smf + 6692;
    float* awl  = smf + 6704;
    float* ahl  = smf + 7216;
    {
        const float2* xc = reinterpret_cast<const float2*>(xcat) + (size_t)n * C_ * S_;
        for (int i = tid; i < TC_ * C_; i += 256) w1s[i] = w1[i];
        __syncthreads();

        float inv[TC_], bas[TC_];
        #pragma unroll
        for (int t = 0; t < TC_; ++t) {
            inv[t] = gam[t] * rsqrtf(var[t] + EPS_);
            bas[t] = bet[t] + (b1[t] - mu[t]) * inv[t];
        }

        {   // s = tid (0..255)
            const int s = tid;
            float acc[16];
            #pragma unroll
            for (int j = 0; j < 16; ++j) acc[j] = 0.f;
            for (int c = 0; c < C_; ++c) {
                const float2 v = xc[c * S_ + s];
                #pragma unroll
                for (int t = 0; t < TC_; ++t) {
                    const float wv = w1s[t * C_ + c];
                    acc[t * 2 + 0] += v.x * wv;
                    acc[t * 2 + 1] += v.y * wv;
                }
            }
            #pragma unroll
            for (int j = 0; j < 16; ++j) {
                const int t = j >> 1;
                float y = acc[j] * inv[t] + bas[t];
                y = y * fminf(fmaxf(y + 3.f, 0.f), 6.f) * (1.f / 6.f);
                ys[s * 17 + j] = y;
            }
        }
        {   // s = 256, parallel: chunk = tid>>4 over c, j = tid&15
            const int j = tid & 15, ch = tid >> 4;
            const int t = j >> 1, kk = j & 1;
            float z = 0.f;
            #pragma unroll
            for (int ci = 0; ci < 16; ++ci) {
                const int c = ch * 16 + ci;
                const float2 v = xc[c * S_ + 256];
                z += (kk ? v.y : v.x) * w1s[t * C_ + c];
            }
            red2[ch * 17 + j] = z;
        }
        __syncthreads();
        if (tid < 16) {
            const int j = tid, t = j >> 1;
            float z = 0.f;
            #pragma unroll
            for (int ch = 0; ch < 16; ++ch) z += red2[ch * 17 + j];
            float y = z * inv[t] + bas[t];
            y = y * fminf(fmaxf(y + 3.f, 0.f), 6.f) * (1.f / 6.f);
            ys[256 * 17 + j] = y;
        }
        __syncthreads();

        if (tid < 4) {    // a_c for my 4 channels
            const int o = c0 + tid;
            float z = b4[o];
            #pragma unroll
            for (int j = 0; j < 16; ++j) z += ys[256 * 17 + j] * w4[o * 16 + j];
            acs[tid] = 1.f / (1.f + expf(-z));
        }
        __syncthreads();

        for (int idx = tid; idx < 4 * 128; idx += 256) {   // 2 iters
            const int u = idx >> 7, h = idx & 127, o = c0 + u;
            float zh = b2[o], zw = b3[o];
            #pragma unroll
            for (int j = 0; j < 16; ++j) {
                zh += ys[h * 17 + j]         * w2[o * 16 + j];
                zw += ys[(128 + h) * 17 + j] * w3[o * 16 + j];
            }
            ahl[idx] = acs[u] / (1.f + expf(-zh));   // a_c folded in
            awl[idx] = 1.f / (1.f + expf(-zw));
        }
        __syncthreads();
    }

    // ---------------- phase 3: out = x * a_h * a_w (own planes, nt stores) --
    {
        const float4* awv = reinterpret_cast<const float4*>(awl);
        for (int u = 0; u < PPB; ++u) {
            const int p = b * PPB + u;
            const f4n* x4 = reinterpret_cast<const f4n*>(x) + (size_t)p * 4096;
            f4n* o4 = reinterpret_cast<f4n*>(out) + (size_t)p * 4096;

            const float4 a = awv[u * 32 + (tid & 31)];   // k-invariant
            #pragma unroll
            for (int k = 0; k < 16; ++k) {
                const int i4 = k * 256 + tid;
                f4n v = x4[i4];
                const float s = ahl[u * 128 + k * 8 + (tid >> 5)];
                v.x *= s * a.x; v.y *= s * a.y; v.z *= s * a.z; v.w *= s * a.w;
                __builtin_nontemporal_store(v, &o4[i4]);
            }
        }
    }
}

extern "C" void kernel_launch(void* const* d_in, const int* in_sizes, int n_in,
                              void* d_out, int out_size, void* d_ws, size_t ws_size,
                              hipStream_t stream) {
    const float* x   = (const float*)d_in[0];
    const float* w1  = (const float*)d_in[1];
    const float* b1  = (const float*)d_in[2];
    const float* gam = (const float*)d_in[3];
    const float* bet = (const float*)d_in[4];
    const float* mu  = (const float*)d_in[5];
    const float* var = (const float*)d_in[6];
    const float* w2  = (const float*)d_in[7];
    const float* b2  = (const float*)d_in[8];
    const float* w3  = (const float*)d_in[9];
    const float* b3  = (const float*)d_in[10];
    const float* w4  = (const float*)d_in[11];
    const float* b4  = (const float*)d_in[12];

    float* ws   = (float*)d_ws;
    float* xcat = ws + XCAT_OFF;
    unsigned* cnt = (unsigned*)(ws + CNT_OFF);
    float* out  = (float*)d_out;

    hipMemsetAsync((void*)cnt, 0, 16 * 16 * sizeof(unsigned), stream);
    mega<<<NBLK, 256, 0, stream>>>(x, w1, b1, gam, bet, mu, var,
                                   w2, b2, w3, b3, w4, b4,
                                   xcat, cnt, out);
}

// Round 9
// 207.922 us; speedup vs baseline: 1.0491x; 1.0491x over previous
//
#include <hip/hip_runtime.h>
#include <math.h>

#define N_ 16
#define C_ 256
#define H_ 128
#define W_ 128
#define TC_ 8
#define S_ 257   // H + W + 1
#define EPS_ 1e-5f
#define NBLK 512
#define BPN 32   // blocks per n
#define PPB 8    // planes per block; b = n*32+cg, channels cg*8..cg*8+7

// ws layout (floats):
//   xcatT: [N][S][2][C] = 2105344   (transposed: c innermost)
//   yg   : [N][S][16]   = 65792
//   cnt  : per-n barrier counters, 64 uints (256 B) per n
#define XCT_OFF 0
#define YG_OFF  2105344
#define CNT_OFF (YG_OFF + 65792)

typedef float f4n __attribute__((ext_vector_type(4)));

__device__ __forceinline__ void nbar(unsigned* c, unsigned target) {
    __syncthreads();
    if (threadIdx.x == 0) {
        __hip_atomic_fetch_add(c, 1u, __ATOMIC_RELEASE, __HIP_MEMORY_SCOPE_AGENT);
        while (__hip_atomic_load(c, __ATOMIC_RELAXED, __HIP_MEMORY_SCOPE_AGENT) < target)
            __builtin_amdgcn_s_sleep(16);
        (void)__hip_atomic_load(c, __ATOMIC_ACQUIRE, __HIP_MEMORY_SCOPE_AGENT);
    }
    __syncthreads();
}

__global__ __launch_bounds__(256, 2) void mega(
    const float* __restrict__ x,
    const float* __restrict__ w1, const float* __restrict__ b1,
    const float* __restrict__ gam, const float* __restrict__ bet,
    const float* __restrict__ mu, const float* __restrict__ var,
    const float* __restrict__ w2, const float* __restrict__ b2,
    const float* __restrict__ w3, const float* __restrict__ b3,
    const float* __restrict__ w4, const float* __restrict__ b4,
    float* __restrict__ xcat, float* __restrict__ yg,
    unsigned* __restrict__ cnt, float* __restrict__ out)
{
    const int b = blockIdx.x;
    const int n = b / BPN, cg = b % BPN;
    const int tid = threadIdx.x;
    __shared__ __align__(16) float smf[9472];   // 37888 B, phase-overlaid

    // xcatT index: [n][s][k][c]
    #define XI(s, k, c) (((size_t)(n * S_ + (s)) * 2 + (k)) * C_ + (c))

    // ---------------- phase 1: stats for my 8 planes -> xcatT ---------------
    {
        float2 (*rowp)[33] = reinterpret_cast<float2(*)[33]>(smf);       // 8448 f
        float4* scr_s = reinterpret_cast<float4*>(smf + 8448);           // 512 f
        float4* scr_m = reinterpret_cast<float4*>(smf + 8960);           // 512 f
        const int rg = tid >> 5;

        for (int u = 0; u < PPB; ++u) {
            const int p = b * PPB + u;          // plane = n*256 + cg*8 + u
            const int c = p & 255;
            const float4* xt = reinterpret_cast<const float4*>(x) + (size_t)p * 4096;

            float4 cs = make_float4(0.f, 0.f, 0.f, 0.f);
            float4 cm = make_float4(-INFINITY, -INFINITY, -INFINITY, -INFINITY);

            #pragma unroll
            for (int k = 0; k < 16; ++k) {
                const float4 v = xt[k * 256 + tid];
                cs.x += v.x; cs.y += v.y; cs.z += v.z; cs.w += v.w;
                cm.x = fmaxf(cm.x, v.x); cm.y = fmaxf(cm.y, v.y);
                cm.z = fmaxf(cm.z, v.z); cm.w = fmaxf(cm.w, v.w);
                const float rs = (v.x + v.y) + (v.z + v.w);
                const float rm = fmaxf(fmaxf(v.x, v.y), fmaxf(v.z, v.w));
                rowp[k * 8 + rg][tid & 31] = make_float2(rs, rm);
            }

            cs.x += __shfl_xor(cs.x, 32); cs.y += __shfl_xor(cs.y, 32);
            cs.z += __shfl_xor(cs.z, 32); cs.w += __shfl_xor(cs.w, 32);
            cm.x = fmaxf(cm.x, __shfl_xor(cm.x, 32));
            cm.y = fmaxf(cm.y, __shfl_xor(cm.y, 32));
            cm.z = fmaxf(cm.z, __shfl_xor(cm.z, 32));
            cm.w = fmaxf(cm.w, __shfl_xor(cm.w, 32));

            const int wv = tid >> 6, ln = tid & 63;
            if (ln < 32) { scr_s[wv * 32 + ln] = cs; scr_m[wv * 32 + ln] = cm; }
            __syncthreads();

            if (tid >= 128) {                    // waves 2-3: row stats
                const int h = tid - 128;
                float2 q0 = rowp[h][0];
                float s = q0.x, m = q0.y;
                #pragma unroll
                for (int j = 1; j < 32; ++j) {
                    const float2 q = rowp[h][j];
                    s += q.x; m = fmaxf(m, q.y);
                }
                xcat[XI(h, 0, c)] = s * (1.f / 128.f);
                xcat[XI(h, 1, c)] = m;
            }

            if (tid < 32) {                      // wave 0: cols + global
                const float4 s0 = scr_s[tid],      s1 = scr_s[32 + tid],
                             s2 = scr_s[64 + tid], s3 = scr_s[96 + tid];
                const float4 m0 = scr_m[tid],      m1 = scr_m[32 + tid],
                             m2 = scr_m[64 + tid], m3 = scr_m[96 + tid];
                float4 S, M;
                S.x = (s0.x + s1.x) + (s2.x + s3.x);
                S.y = (s0.y + s1.y) + (s2.y + s3.y);
                S.z = (s0.z + s1.z) + (s2.z + s3.z);
                S.w = (s0.w + s1.w) + (s2.w + s3.w);
                M.x = fmaxf(fmaxf(m0.x, m1.x), fmaxf(m2.x, m3.x));
                M.y = fmaxf(fmaxf(m0.y, m1.y), fmaxf(m2.y, m3.y));
                M.z = fmaxf(fmaxf(m0.z, m1.z), fmaxf(m2.z, m3.z));
                M.w = fmaxf(fmaxf(m0.w, m1.w), fmaxf(m2.w, m3.w));

                const int w0 = 4 * tid;
                xcat[XI(128 + w0 + 0, 0, c)] = S.x * (1.f / 128.f);
                xcat[XI(128 + w0 + 0, 1, c)] = M.x;
                xcat[XI(128 + w0 + 1, 0, c)] = S.y * (1.f / 128.f);
                xcat[XI(128 + w0 + 1, 1, c)] = M.y;
                xcat[XI(128 + w0 + 2, 0, c)] = S.z * (1.f / 128.f);
                xcat[XI(128 + w0 + 2, 1, c)] = M.z;
                xcat[XI(128 + w0 + 3, 0, c)] = S.w * (1.f / 128.f);
                xcat[XI(128 + w0 + 3, 1, c)] = M.w;

                float gs = (S.x + S.y) + (S.z + S.w);
                float gm = fmaxf(fmaxf(M.x, M.y), fmaxf(M.z, M.w));
                #pragma unroll
                for (int m = 16; m >= 1; m >>= 1) {
                    gs += __shfl_xor(gs, m);
                    gm = fmaxf(gm, __shfl_xor(gm, m));
                }
                if (tid == 0) {
                    xcat[XI(256, 0, c)] = gs * (1.f / 16384.f);
                    xcat[XI(256, 1, c)] = gm;
                }
            }
            __syncthreads();
        }
    }

    // ------------- barrier 1: all 32 siblings of my n done with stats -------
    nbar(cnt + n * 64, BPN);

    // ---------------- phase 2a: distributed y (each block: 8 s-positions) ---
    {
        float* red = smf;   // [(si*16+j)*33 + cgp] = 4224 floats
        const int si = tid >> 5, cgp = tid & 31, c0 = cgp * 8;

        float4 w1r[8][2];
        #pragma unroll
        for (int t = 0; t < 8; ++t) {
            w1r[t][0] = *reinterpret_cast<const float4*>(w1 + t * C_ + c0);
            w1r[t][1] = *reinterpret_cast<const float4*>(w1 + t * C_ + c0 + 4);
        }

        const int s = cg * 8 + si;
        float acc[16];
        #pragma unroll
        for (int j = 0; j < 16; ++j) acc[j] = 0.f;
        {
            const float4 mnA = *reinterpret_cast<const float4*>(&xcat[XI(s, 0, c0)]);
            const float4 mnB = *reinterpret_cast<const float4*>(&xcat[XI(s, 0, c0 + 4)]);
            const float4 mxA = *reinterpret_cast<const float4*>(&xcat[XI(s, 1, c0)]);
            const float4 mxB = *reinterpret_cast<const float4*>(&xcat[XI(s, 1, c0 + 4)]);
            #pragma unroll
            for (int t = 0; t < 8; ++t) {
                const float4 wa = w1r[t][0], wb = w1r[t][1];
                acc[t * 2 + 0] = (mnA.x * wa.x + mnA.y * wa.y + mnA.z * wa.z + mnA.w * wa.w)
                               + (mnB.x * wb.x + mnB.y * wb.y + mnB.z * wb.z + mnB.w * wb.w);
                acc[t * 2 + 1] = (mxA.x * wa.x + mxA.y * wa.y + mxA.z * wa.z + mxA.w * wa.w)
                               + (mxB.x * wb.x + mxB.y * wb.y + mxB.z * wb.z + mxB.w * wb.w);
            }
        }
        #pragma unroll
        for (int j = 0; j < 16; ++j) red[(si * 16 + j) * 33 + cgp] = acc[j];
        __syncthreads();

        if (tid < 128) {   // reduce over 32 c-groups; (si2, j)
            const int si2 = tid >> 4, j = tid & 15, t = j >> 1;
            float z = 0.f;
            #pragma unroll
            for (int g = 0; g < 32; ++g) z += red[(si2 * 16 + j) * 33 + g];
            const float inv = gam[t] * rsqrtf(var[t] + EPS_);
            float y = (z + b1[t] - mu[t]) * inv + bet[t];
            y = y * fminf(fmaxf(y + 3.f, 0.f), 6.f) * (1.f / 6.f);
            yg[((size_t)n * S_ + cg * 8 + si2) * 16 + j] = y;
        }

        if (cg == BPN - 1) {   // tail s = 256 (block-uniform branch)
            __syncthreads();
            float* red2 = smf;           // [256][17] = 4352
            float* redB = smf + 4352;    // [16][17]  = 272
            const float mn = xcat[XI(256, 0, tid)];
            const float mx = xcat[XI(256, 1, tid)];
            float pj[16];
            #pragma unroll
            for (int t = 0; t < 8; ++t) {
                const float w = w1[t * C_ + tid];
                pj[t * 2 + 0] = mn * w;
                pj[t * 2 + 1] = mx * w;
            }
            #pragma unroll
            for (int j = 0; j < 16; ++j) red2[tid * 17 + j] = pj[j];
            __syncthreads();
            {   // level 1: g = tid>>4, j = tid&15
                const int g = tid >> 4, j = tid & 15;
                float z = 0.f;
                #pragma unroll
                for (int m = 0; m < 16; ++m) z += red2[(g * 16 + m) * 17 + j];
                redB[j * 17 + g] = z;
            }
            __syncthreads();
            if (tid < 16) {
                const int j = tid, t = j >> 1;
                float z = 0.f;
                #pragma unroll
                for (int g = 0; g < 16; ++g) z += redB[j * 17 + g];
                const float inv = gam[t] * rsqrtf(var[t] + EPS_);
                float y = (z + b1[t] - mu[t]) * inv + bet[t];
                y = y * fminf(fmaxf(y + 3.f, 0.f), 6.f) * (1.f / 6.f);
                yg[((size_t)n * S_ + 256) * 16 + j] = y;
            }
        }
    }

    // ------------- barrier 2: y[n] complete ---------------------------------
    nbar(cnt + n * 64 + 32, BPN);

    // ---------------- phase 2b: own 8 channels' a_h (x a_c), a_w in LDS -----
    float* ys  = smf;            // 4369 (padded [s][17])
    float* acs = smf + 4370;     // 8
    float* awl = smf + 4384;     // 1024 (byte 17536, 16B-aligned)
    float* ahl = smf + 5408;     // 1024
    {
        for (int i = tid; i < S_ * 16; i += 256)
            ys[(i >> 4) * 17 + (i & 15)] = yg[(size_t)n * S_ * 16 + i];
        __syncthreads();

        if (tid < 8) {
            const int o = cg * 8 + tid;
            float z = b4[o];
            #pragma unroll
            for (int j = 0; j < 16; ++j) z += ys[256 * 17 + j] * w4[o * 16 + j];
            acs[tid] = 1.f / (1.f + expf(-z));
        }
        __syncthreads();

        for (int idx = tid; idx < 8 * 128; idx += 256) {
            const int u = idx >> 7, h = idx & 127, o = cg * 8 + u;
            float zh = b2[o], zw = b3[o];
            #pragma unroll
            for (int j = 0; j < 16; ++j) {
                zh += ys[h * 17 + j]         * w2[o * 16 + j];
                zw += ys[(128 + h) * 17 + j] * w3[o * 16 + j];
            }
            ahl[idx] = acs[u] / (1.f + expf(-zh));   // a_c folded in
            awl[idx] = 1.f / (1.f + expf(-zw));
        }
        __syncthreads();
    }

    // ---------------- phase 3: out = x * a_h * a_w (own planes, nt stores) --
    {
        const float4* awv = reinterpret_cast<const float4*>(awl);
        for (int u = 0; u < PPB; ++u) {
            const int p = b * PPB + u;
            const f4n* x4 = reinterpret_cast<const f4n*>(x) + (size_t)p * 4096;
            f4n* o4 = reinterpret_cast<f4n*>(out) + (size_t)p * 4096;

            const float4 a = awv[u * 32 + (tid & 31)];   // k-invariant
            #pragma unroll
            for (int k = 0; k < 16; ++k) {
                const int i4 = k * 256 + tid;
                f4n v = x4[i4];
                const float s = ahl[u * 128 + k * 8 + (tid >> 5)];
                v.x *= s * a.x; v.y *= s * a.y; v.z *= s * a.z; v.w *= s * a.w;
                __builtin_nontemporal_store(v, &o4[i4]);
            }
        }
    }
    #undef XI
}

extern "C" void kernel_launch(void* const* d_in, const int* in_sizes, int n_in,
                              void* d_out, int out_size, void* d_ws, size_t ws_size,
                              hipStream_t stream) {
    const float* x   = (const float*)d_in[0];
    const float* w1  = (const float*)d_in[1];
    const float* b1  = (const float*)d_in[2];
    const float* gam = (const float*)d_in[3];
    const float* bet = (const float*)d_in[4];
    const float* mu  = (const float*)d_in[5];
    const float* var = (const float*)d_in[6];
    const float* w2  = (const float*)d_in[7];
    const float* b2  = (const float*)d_in[8];
    const float* w3  = (const float*)d_in[9];
    const float* b3  = (const float*)d_in[10];
    const float* w4  = (const float*)d_in[11];
    const float* b4  = (const float*)d_in[12];

    float* ws   = (float*)d_ws;
    float* xcat = ws + XCT_OFF;
    float* yg   = ws + YG_OFF;
    unsigned* cnt = (unsigned*)(ws + CNT_OFF);
    float* out  = (float*)d_out;

    hipMemsetAsync((void*)cnt, 0, 16 * 64 * sizeof(unsigned), stream);
    mega<<<NBLK, 256, 0, stream>>>(x, w1, b1, gam, bet, mu, var,
                                   w2, b2, w3, b3, w4, b4,
                                   xcat, yg, cnt, out);
}

// Round 10
// 175.477 us; speedup vs baseline: 1.2431x; 1.1849x over previous
//
#include <hip/hip_runtime.h>
#include <math.h>

#define N_ 16
#define C_ 256
#define H_ 128
#define W_ 128
#define TC_ 8
#define S_ 257   // H + W + 1
#define EPS_ 1e-5f
#define NBLK 512
#define BPN 32   // blocks per n
#define PPB 8    // planes per block; b = n*32+cg, channels c0 = cg*8..+8

// ws layout (floats):
//   xcat : [N*C][S][2] = 2105344   (contiguous per-plane writes)
//   ahg  : [N*C][H]    = 524288    (pure sigmoid, a_c folded at phase 3)
//   awg  : [N*C][W]    = 524288
//   y256g: [N][16]     = 256
//   cnt  : per-n, 64 uints (barrier1 at +0, barrier2 at +32 -> separate lines)
#define XCT_OFF  0
#define AH_OFF   2105344
#define AW_OFF   (AH_OFF + 524288)
#define Y256_OFF (AW_OFF + 524288)
#define CNT_OFF  (Y256_OFF + 256)

typedef float f4n __attribute__((ext_vector_type(4)));

__device__ __forceinline__ void nbar(unsigned* c, unsigned target) {
    __syncthreads();
    if (threadIdx.x == 0) {
        __hip_atomic_fetch_add(c, 1u, __ATOMIC_RELEASE, __HIP_MEMORY_SCOPE_AGENT);
        while (__hip_atomic_load(c, __ATOMIC_RELAXED, __HIP_MEMORY_SCOPE_AGENT) < target)
            __builtin_amdgcn_s_sleep(16);
        (void)__hip_atomic_load(c, __ATOMIC_ACQUIRE, __HIP_MEMORY_SCOPE_AGENT);
    }
    __syncthreads();
}

__global__ __launch_bounds__(256, 2) void mega(
    const float* __restrict__ x,
    const float* __restrict__ w1, const float* __restrict__ b1,
    const float* __restrict__ gam, const float* __restrict__ bet,
    const float* __restrict__ mu, const float* __restrict__ var,
    const float* __restrict__ w2, const float* __restrict__ b2,
    const float* __restrict__ w3, const float* __restrict__ b3,
    const float* __restrict__ w4, const float* __restrict__ b4,
    float* __restrict__ xcat, float* __restrict__ ahg, float* __restrict__ awg,
    float* __restrict__ y256g, unsigned* __restrict__ cnt,
    float* __restrict__ out)
{
    const int b = blockIdx.x;
    const int n = b >> 5, cg = b & 31, c0 = cg * 8;
    const int tid = threadIdx.x;
    __shared__ __align__(16) float smf[9472];   // 37888 B, phase-overlaid

    // ---------------- phase 1: stats for my 8 planes -> xcat[c][s][2] -------
    {
        float2 (*rowp)[33] = reinterpret_cast<float2(*)[33]>(smf);       // 8448 f
        float4* scr_s = reinterpret_cast<float4*>(smf + 8448);           // 512 f
        float4* scr_m = reinterpret_cast<float4*>(smf + 8960);           // 512 f
        const int rg = tid >> 5;

        for (int u = 0; u < PPB; ++u) {
            const int p = b * PPB + u;
            const float4* xt = reinterpret_cast<const float4*>(x) + (size_t)p * 4096;
            float2* xcat2 = reinterpret_cast<float2*>(xcat) + (size_t)p * S_;

            float4 cs = make_float4(0.f, 0.f, 0.f, 0.f);
            float4 cm = make_float4(-INFINITY, -INFINITY, -INFINITY, -INFINITY);

            #pragma unroll
            for (int k = 0; k < 16; ++k) {
                const float4 v = xt[k * 256 + tid];
                cs.x += v.x; cs.y += v.y; cs.z += v.z; cs.w += v.w;
                cm.x = fmaxf(cm.x, v.x); cm.y = fmaxf(cm.y, v.y);
                cm.z = fmaxf(cm.z, v.z); cm.w = fmaxf(cm.w, v.w);
                const float rs = (v.x + v.y) + (v.z + v.w);
                const float rm = fmaxf(fmaxf(v.x, v.y), fmaxf(v.z, v.w));
                rowp[k * 8 + rg][tid & 31] = make_float2(rs, rm);
            }

            cs.x += __shfl_xor(cs.x, 32); cs.y += __shfl_xor(cs.y, 32);
            cs.z += __shfl_xor(cs.z, 32); cs.w += __shfl_xor(cs.w, 32);
            cm.x = fmaxf(cm.x, __shfl_xor(cm.x, 32));
            cm.y = fmaxf(cm.y, __shfl_xor(cm.y, 32));
            cm.z = fmaxf(cm.z, __shfl_xor(cm.z, 32));
            cm.w = fmaxf(cm.w, __shfl_xor(cm.w, 32));

            const int wv = tid >> 6, ln = tid & 63;
            if (ln < 32) { scr_s[wv * 32 + ln] = cs; scr_m[wv * 32 + ln] = cm; }
            __syncthreads();

            if (tid >= 128) {                    // waves 2-3: row stats
                const int h = tid - 128;
                float2 q0 = rowp[h][0];
                float s = q0.x, m = q0.y;
                #pragma unroll
                for (int j = 1; j < 32; ++j) {
                    const float2 q = rowp[h][j];
                    s += q.x; m = fmaxf(m, q.y);
                }
                xcat2[h] = make_float2(s * (1.f / 128.f), m);
            }

            if (tid < 32) {                      // wave 0: cols + global
                const float4 s0 = scr_s[tid],      s1 = scr_s[32 + tid],
                             s2 = scr_s[64 + tid], s3 = scr_s[96 + tid];
                const float4 m0 = scr_m[tid],      m1 = scr_m[32 + tid],
                             m2 = scr_m[64 + tid], m3 = scr_m[96 + tid];
                float4 S, M;
                S.x = (s0.x + s1.x) + (s2.x + s3.x);
                S.y = (s0.y + s1.y) + (s2.y + s3.y);
                S.z = (s0.z + s1.z) + (s2.z + s3.z);
                S.w = (s0.w + s1.w) + (s2.w + s3.w);
                M.x = fmaxf(fmaxf(m0.x, m1.x), fmaxf(m2.x, m3.x));
                M.y = fmaxf(fmaxf(m0.y, m1.y), fmaxf(m2.y, m3.y));
                M.z = fmaxf(fmaxf(m0.z, m1.z), fmaxf(m2.z, m3.z));
                M.w = fmaxf(fmaxf(m0.w, m1.w), fmaxf(m2.w, m3.w));

                const int w0 = 4 * tid;
                xcat2[128 + w0 + 0] = make_float2(S.x * (1.f / 128.f), M.x);
                xcat2[128 + w0 + 1] = make_float2(S.y * (1.f / 128.f), M.y);
                xcat2[128 + w0 + 2] = make_float2(S.z * (1.f / 128.f), M.z);
                xcat2[128 + w0 + 3] = make_float2(S.w * (1.f / 128.f), M.w);

                float gs = (S.x + S.y) + (S.z + S.w);
                float gm = fmaxf(fmaxf(M.x, M.y), fmaxf(M.z, M.w));
                #pragma unroll
                for (int m = 16; m >= 1; m >>= 1) {
                    gs += __shfl_xor(gs, m);
                    gm = fmaxf(gm, __shfl_xor(gm, m));
                }
                if (tid == 0) xcat2[256] = make_float2(gs * (1.f / 16384.f), gm);
            }
            __syncthreads();
        }
    }

    // ------------- barrier 1: all 32 siblings of my n done with stats -------
    nbar(cnt + n * 64, BPN);

    // ---------------- phase 2: y at my 8 s-positions -> attention rows ------
    // LDS overlay: w1s 0..2048 | red 2048..6272 ([si][j][33]) | ys 6272..6408
    {
        float* w1s = smf;
        float* red = smf + 2048;
        float* ys  = smf + 6272;
        const float2* xc2 = reinterpret_cast<const float2*>(xcat) + (size_t)n * C_ * S_;
        const int s0 = cg * 8;

        for (int i = tid; i < TC_ * C_; i += 256) w1s[i] = w1[i];
        __syncthreads();

        {   // stage A: partial einsum; thread = (cgrp = tid>>3, si = tid&7)
            const int cgrp = tid >> 3, si = tid & 7;
            const int s = s0 + si;
            float acc[16];
            #pragma unroll
            for (int j = 0; j < 16; ++j) acc[j] = 0.f;
            #pragma unroll
            for (int i = 0; i < 8; ++i) {
                const int c = cgrp * 8 + i;
                const float2 v = xc2[c * S_ + s];
                #pragma unroll
                for (int t = 0; t < TC_; ++t) {
                    const float w = w1s[t * C_ + c];
                    acc[t * 2 + 0] += v.x * w;
                    acc[t * 2 + 1] += v.y * w;
                }
            }
            #pragma unroll
            for (int j = 0; j < 16; ++j) red[(si * 16 + j) * 33 + cgrp] = acc[j];
        }
        __syncthreads();

        if (tid < 128) {   // stage B: reduce 32 c-groups, BN + hswish -> ys
            const int si2 = tid >> 4, j = tid & 15, t = j >> 1;
            float z = 0.f;
            #pragma unroll
            for (int g = 0; g < 32; ++g) z += red[(si2 * 16 + j) * 33 + g];
            const float inv = gam[t] * rsqrtf(var[t] + EPS_);
            float y = (z + b1[t] - mu[t]) * inv + bet[t];
            y = y * fminf(fmaxf(y + 3.f, 0.f), 6.f) * (1.f / 6.f);
            ys[si2 * 17 + j] = y;
        }
        __syncthreads();

        if (cg == BPN - 1) {   // tail s = 256 -> y256g (block-uniform branch)
            const int c = tid;
            const float2 v = xc2[c * S_ + 256];
            float pj[16];
            #pragma unroll
            for (int t = 0; t < TC_; ++t) {
                const float w = w1s[t * C_ + c];
                pj[t * 2 + 0] = v.x * w;
                pj[t * 2 + 1] = v.y * w;
            }
            __syncthreads();               // done with w1s/red
            float* red2 = smf;             // [256][17]
            float* redB = smf + 4400;      // [16][17]
            #pragma unroll
            for (int j = 0; j < 16; ++j) red2[tid * 17 + j] = pj[j];
            __syncthreads();
            {
                const int g = tid >> 4, j = tid & 15;
                float z = 0.f;
                #pragma unroll
                for (int m = 0; m < 16; ++m) z += red2[(g * 16 + m) * 17 + j];
                redB[j * 17 + g] = z;
            }
            __syncthreads();
            if (tid < 16) {
                const int j = tid, t = j >> 1;
                float z = 0.f;
                #pragma unroll
                for (int g = 0; g < 16; ++g) z += redB[j * 17 + g];
                const float inv = gam[t] * rsqrtf(var[t] + EPS_);
                float y = (z + b1[t] - mu[t]) * inv + bet[t];
                y = y * fminf(fmaxf(y + 3.f, 0.f), 6.f) * (1.f / 6.f);
                y256g[n * 16 + j] = y;
            }
            __syncthreads();
        }

        {   // stage C: attention row for ALL 256 channels at my 8 s-positions
            const int o = tid;
            const bool is_h = (cg < 16);
            const float* wX = is_h ? w2 : w3;
            const float zb = is_h ? b2[o] : b3[o];
            float4 wr[4];
            const float4* wv = reinterpret_cast<const float4*>(wX + o * 16);
            #pragma unroll
            for (int q = 0; q < 4; ++q) wr[q] = wv[q];

            float r[8];
            #pragma unroll
            for (int si = 0; si < 8; ++si) {
                float z = zb;
                #pragma unroll
                for (int q = 0; q < 4; ++q) {
                    z += ys[si * 17 + q * 4 + 0] * wr[q].x
                       + ys[si * 17 + q * 4 + 1] * wr[q].y
                       + ys[si * 17 + q * 4 + 2] * wr[q].z
                       + ys[si * 17 + q * 4 + 3] * wr[q].w;
                }
                r[si] = 1.f / (1.f + expf(-z));
            }
            float* og = is_h ? (ahg + (size_t)(n * C_ + o) * H_ + s0)
                             : (awg + (size_t)(n * C_ + o) * W_ + (s0 - 128));
            *reinterpret_cast<float4*>(og)     = make_float4(r[0], r[1], r[2], r[3]);
            *reinterpret_cast<float4*>(og + 4) = make_float4(r[4], r[5], r[6], r[7]);
        }
    }

    // ------------- barrier 2: all attention rows of my n complete -----------
    nbar(cnt + n * 64 + 32, BPN);

    // ---------------- phase 3: stage own channels, stream, nt-store ---------
    float* acs = smf;            // 8
    float* ahl = smf + 16;       // 1024
    float* awl = smf + 1040;     // 1024
    {
        if (tid < 8) {
            const int o = c0 + tid;
            float z = b4[o];
            #pragma unroll
            for (int j = 0; j < 16; ++j) z += y256g[n * 16 + j] * w4[o * 16 + j];
            acs[tid] = 1.f / (1.f + expf(-z));
        }
        __syncthreads();

        for (int idx = tid; idx < 8 * 128; idx += 256) {
            const int u = idx >> 7, h = idx & 127, o = c0 + u;
            ahl[idx] = acs[u] * ahg[(size_t)(n * C_ + o) * H_ + h];
            awl[idx] = awg[(size_t)(n * C_ + o) * W_ + h];
        }
        __syncthreads();
    }
    {
        const float4* awv = reinterpret_cast<const float4*>(awl);
        for (int u = 0; u < PPB; ++u) {
            const int p = b * PPB + u;
            const f4n* x4 = reinterpret_cast<const f4n*>(x) + (size_t)p * 4096;
            f4n* o4 = reinterpret_cast<f4n*>(out) + (size_t)p * 4096;

            const float4 a = awv[u * 32 + (tid & 31)];   // k-invariant
            #pragma unroll
            for (int k = 0; k < 16; ++k) {
                const int i4 = k * 256 + tid;
                f4n v = x4[i4];
                const float s = ahl[u * 128 + k * 8 + (tid >> 5)];
                v.x *= s * a.x; v.y *= s * a.y; v.z *= s * a.z; v.w *= s * a.w;
                __builtin_nontemporal_store(v, &o4[i4]);
            }
        }
    }
}

extern "C" void kernel_launch(void* const* d_in, const int* in_sizes, int n_in,
                              void* d_out, int out_size, void* d_ws, size_t ws_size,
                              hipStream_t stream) {
    const float* x   = (const float*)d_in[0];
    const float* w1  = (const float*)d_in[1];
    const float* b1  = (const float*)d_in[2];
    const float* gam = (const float*)d_in[3];
    const float* bet = (const float*)d_in[4];
    const float* mu  = (const float*)d_in[5];
    const float* var = (const float*)d_in[6];
    const float* w2  = (const float*)d_in[7];
    const float* b2  = (const float*)d_in[8];
    const float* w3  = (const float*)d_in[9];
    const float* b3  = (const float*)d_in[10];
    const float* w4  = (const float*)d_in[11];
    const float* b4  = (const float*)d_in[12];

    float* ws    = (float*)d_ws;
    float* xcat  = ws + XCT_OFF;
    float* ahg   = ws + AH_OFF;
    float* awg   = ws + AW_OFF;
    float* y256g = ws + Y256_OFF;
    unsigned* cnt = (unsigned*)(ws + CNT_OFF);
    float* out   = (float*)d_out;

    hipMemsetAsync((void*)cnt, 0, 16 * 64 * sizeof(unsigned), stream);
    mega<<<NBLK, 256, 0, stream>>>(x, w1, b1, gam, bet, mu, var,
                                   w2, b2, w3, b3, w4, b4,
                                   xcat, ahg, awg, y256g, cnt, out);
}